// Round 4
// baseline (758.960 us; speedup 1.0000x reference)
//
#include <hip/hip_runtime.h>
#include <hip/hip_bf16.h>
#include <math.h>

typedef __bf16 bf16x8 __attribute__((ext_vector_type(8)));
typedef __bf16 bf16x4 __attribute__((ext_vector_type(4)));
typedef float f32x4 __attribute__((ext_vector_type(4)));

#define AS1 __attribute__((address_space(1)))
#define AS3 __attribute__((address_space(3)))

__device__ __forceinline__ void gll16(const __bf16* g, __bf16* l) {
    __builtin_amdgcn_global_load_lds((const AS1 unsigned int*)g,
                                     (AS3 unsigned int*)l, 16, 0, 0);
}

__device__ __forceinline__ unsigned pkbf(float a, float b) {
    union { __bf16 h[2]; unsigned u; } t;
    t.h[0] = (__bf16)a; t.h[1] = (__bf16)b;
    return t.u;
}

// ---------------------------------------------------------------------------
// All 6 weight transposes (fp32 [K,N] -> bf16 [N,K]) in one launch.
// ---------------------------------------------------------------------------
__global__ __launch_bounds__(256) void transpose_all(
    const float* __restrict__ Wq, const float* __restrict__ Wk,
    const float* __restrict__ Wv, const float* __restrict__ Wo,
    const float* __restrict__ W1, const float* __restrict__ W2,
    __bf16* __restrict__ Wqt, __bf16* __restrict__ Wkt,
    __bf16* __restrict__ Wvt, __bf16* __restrict__ Wot,
    __bf16* __restrict__ W1t, __bf16* __restrict__ W2t) {
    int g = blockIdx.x;
    const float* W; __bf16* Wt; int K, N, kt, nt;
    if (g < 4096) {
        int mi = g >> 10, loc = g & 1023;
        K = 1024; N = 1024; kt = loc >> 5; nt = loc & 31;
        W  = mi == 0 ? Wq  : mi == 1 ? Wk  : mi == 2 ? Wv  : Wo;
        Wt = mi == 0 ? Wqt : mi == 1 ? Wkt : mi == 2 ? Wvt : Wot;
    } else if (g < 8192) {
        int loc = g - 4096; W = W1; Wt = W1t;
        K = 1024; N = 4096; kt = loc >> 7; nt = loc & 127;
    } else {
        int loc = g - 8192; W = W2; Wt = W2t;
        K = 4096; N = 1024; kt = loc >> 5; nt = loc & 31;
    }
    int k0 = kt * 32, n0 = nt * 32;
    __shared__ float tile[32][33];
    int tx = threadIdx.x & 31, ty = threadIdx.x >> 5;
    #pragma unroll
    for (int j = ty; j < 32; j += 8)
        tile[j][tx] = W[(size_t)(k0 + j) * N + n0 + tx];
    __syncthreads();
    #pragma unroll
    for (int j = ty; j < 32; j += 8)
        Wt[(size_t)(n0 + j) * K + k0 + tx] = (__bf16)tile[tx][j];
}

// ---------------------------------------------------------------------------
// Fused 3-way pre-norm.
// ---------------------------------------------------------------------------
__global__ __launch_bounds__(256) void ln3_kernel(
    const float* __restrict__ q, const float* __restrict__ k,
    const float* __restrict__ v,
    const float* __restrict__ g1, const float* __restrict__ b1,
    const float* __restrict__ g2, const float* __restrict__ b2,
    float* __restrict__ qln, __bf16* __restrict__ qbf,
    __bf16* __restrict__ kbf, __bf16* __restrict__ vbf) {
    const int E = 1024;
    int which = blockIdx.y;
    const float* x = which == 0 ? q : which == 1 ? k : v;
    const float* g = which == 0 ? g1 : g2;
    const float* bb = which == 0 ? b1 : b2;
    float* o32 = which == 0 ? qln : nullptr;
    __bf16* obf = which == 0 ? qbf : which == 1 ? kbf : vbf;

    size_t row = blockIdx.x;
    int t = threadIdx.x;
    float4 val = ((const float4*)(x + row * E))[t];
    float s  = val.x + val.y + val.z + val.w;
    float s2 = val.x * val.x + val.y * val.y + val.z * val.z + val.w * val.w;
    #pragma unroll
    for (int off = 32; off >= 1; off >>= 1) {
        s  += __shfl_down(s, off);
        s2 += __shfl_down(s2, off);
    }
    __shared__ float red[2][4];
    int wid = t >> 6, lane = t & 63;
    if (lane == 0) { red[0][wid] = s; red[1][wid] = s2; }
    __syncthreads();
    if (t == 0) {
        float S1 = red[0][0] + red[0][1] + red[0][2] + red[0][3];
        float S2 = red[1][0] + red[1][1] + red[1][2] + red[1][3];
        float mean = S1 / E;
        float var  = S2 / E - mean * mean;
        red[0][0] = mean;
        red[1][0] = 1.0f / sqrtf(var + 1e-5f);
    }
    __syncthreads();
    float mean = red[0][0], rstd = red[1][0];
    float4 gv = ((const float4*)g)[t];
    float4 bv = ((const float4*)bb)[t];
    float y0 = (val.x - mean) * rstd * gv.x + bv.x;
    float y1 = (val.y - mean) * rstd * gv.y + bv.y;
    float y2 = (val.z - mean) * rstd * gv.z + bv.z;
    float y3 = (val.w - mean) * rstd * gv.w + bv.w;
    if (o32) ((float4*)(o32 + row * E))[t] = make_float4(y0, y1, y2, y3);
    bf16x4 o;
    o[0] = (__bf16)y0; o[1] = (__bf16)y1; o[2] = (__bf16)y2; o[3] = (__bf16)y3;
    ((bf16x4*)(obf + row * E))[t] = o;
}

// single-input LN (final norm), bf16 out
__global__ __launch_bounds__(256) void ln_kernel(const float* __restrict__ x,
                                                 const float* __restrict__ g,
                                                 const float* __restrict__ bb,
                                                 __bf16* __restrict__ outbf) {
    const int E = 1024;
    size_t row = blockIdx.x;
    int t = threadIdx.x;
    float4 v = ((const float4*)(x + row * E))[t];
    float s  = v.x + v.y + v.z + v.w;
    float s2 = v.x * v.x + v.y * v.y + v.z * v.z + v.w * v.w;
    #pragma unroll
    for (int off = 32; off >= 1; off >>= 1) {
        s  += __shfl_down(s, off);
        s2 += __shfl_down(s2, off);
    }
    __shared__ float red[2][4];
    int wid = t >> 6, lane = t & 63;
    if (lane == 0) { red[0][wid] = s; red[1][wid] = s2; }
    __syncthreads();
    if (t == 0) {
        float S1 = red[0][0] + red[0][1] + red[0][2] + red[0][3];
        float S2 = red[1][0] + red[1][1] + red[1][2] + red[1][3];
        float mean = S1 / E;
        float var  = S2 / E - mean * mean;
        red[0][0] = mean;
        red[1][0] = 1.0f / sqrtf(var + 1e-5f);
    }
    __syncthreads();
    float mean = red[0][0], rstd = red[1][0];
    float4 gv = ((const float4*)g)[t];
    float4 bv = ((const float4*)bb)[t];
    bf16x4 o;
    o[0] = (__bf16)((v.x - mean) * rstd * gv.x + bv.x);
    o[1] = (__bf16)((v.y - mean) * rstd * gv.y + bv.y);
    o[2] = (__bf16)((v.z - mean) * rstd * gv.z + bv.z);
    o[3] = (__bf16)((v.w - mean) * rstd * gv.w + bv.w);
    ((bf16x4*)(outbf + row * E))[t] = o;
}

// ---------------------------------------------------------------------------
// Templated GEMM: tile = (TMD*32) x (TND*32), 4 waves (2x2), swapped-operand
// MFMA so accumulators are C^T-laid-out (lane: row=l15, col=quad*4+r).
// EPI: 1 f32 out + bias + resid; 2 bf16 out + bias + gelu.
// ---------------------------------------------------------------------------
template <int EPI, int TMD, int TND>
__global__ __launch_bounds__(256) void gemm_tn(const __bf16* __restrict__ A,
                                               const __bf16* __restrict__ Bt,
                                               const float* __restrict__ bias,
                                               const float* __restrict__ resid,
                                               void* __restrict__ Cout,
                                               int M, int N, int K) {
    __shared__ __bf16 As[TMD * 32 * 64];
    __shared__ __bf16 Bs[TND * 32 * 64];
    int tid  = threadIdx.x;
    int lane = tid & 63, wid = tid >> 6;
    int quad = lane >> 4, l15 = lane & 15;
    int waveM = wid >> 1, waveN = wid & 1;
    size_t rowBase = (size_t)blockIdx.y * (TMD * 32);
    size_t colBase = (size_t)blockIdx.x * (TND * 32);

    int lrow8  = lane >> 3;
    int lchunk = (lane & 7) ^ lrow8;
    const __bf16* Ag0 = A  + (rowBase + wid * (8 * TMD) + lrow8) * (size_t)K + lchunk * 8;
    const __bf16* Bg0 = Bt + (colBase + wid * (8 * TND) + lrow8) * (size_t)K + lchunk * 8;
    __bf16* AsB = &As[(wid * 8 * TMD) * 64];
    __bf16* BsB = &Bs[(wid * 8 * TND) * 64];

    f32x4 acc[TMD][TND] = {};
    int swz = l15 & 7;

    for (int kb = 0; kb < K; kb += 64) {
        __syncthreads();
        #pragma unroll
        for (int i = 0; i < TMD; i++)
            gll16(Ag0 + (size_t)i * 8 * K + kb, AsB + i * 512);
        #pragma unroll
        for (int i = 0; i < TND; i++)
            gll16(Bg0 + (size_t)i * 8 * K + kb, BsB + i * 512);
        __syncthreads();
        #pragma unroll
        for (int ks = 0; ks < 2; ks++) {
            int p = ((ks * 4 + quad) ^ swz) * 8;
            bf16x8 af[TMD], bfr[TND];
            #pragma unroll
            for (int mi = 0; mi < TMD; mi++)
                af[mi] = *(const bf16x8*)&As[(waveM * 16 * TMD + mi * 16 + l15) * 64 + p];
            #pragma unroll
            for (int ni = 0; ni < TND; ni++)
                bfr[ni] = *(const bf16x8*)&Bs[(waveN * 16 * TND + ni * 16 + l15) * 64 + p];
            #pragma unroll
            for (int mi = 0; mi < TMD; mi++)
                #pragma unroll
                for (int ni = 0; ni < TND; ni++)
                    acc[mi][ni] = __builtin_amdgcn_mfma_f32_16x16x32_bf16(
                        bfr[ni], af[mi], acc[mi][ni], 0, 0, 0);  // swapped: C^T
        }
    }

    #pragma unroll
    for (int mi = 0; mi < TMD; mi++)
    #pragma unroll
    for (int ni = 0; ni < TND; ni++) {
        size_t row = rowBase + waveM * 16 * TMD + mi * 16 + l15;
        size_t col = colBase + waveN * 16 * TND + ni * 16 + quad * 4;
        f32x4 v = acc[mi][ni];
        if (EPI == 1) {
            float4 b4 = *(const float4*)&bias[col];
            float4 r4 = *(const float4*)&resid[row * N + col];
            float4 o;
            o.x = v[0] + b4.x + r4.x; o.y = v[1] + b4.y + r4.y;
            o.z = v[2] + b4.z + r4.z; o.w = v[3] + b4.w + r4.w;
            *(float4*)&((float*)Cout)[row * N + col] = o;
        } else {
            float4 b4 = *(const float4*)&bias[col];
            bf16x4 pk;
            #pragma unroll
            for (int r = 0; r < 4; r++) {
                float t2 = v[r] + ((const float*)&b4)[r];
                pk[r] = (__bf16)(0.5f * t2 * (1.0f + erff(t2 * 0.70710678118654752f)));
            }
            *(bf16x4*)&((__bf16*)Cout)[row * N + col] = pk;
        }
    }
}

// ---------------------------------------------------------------------------
// Merged QKV projection. grid.x: 0..7 -> Q (scaled 1/8, row-major QKb),
// 8..15 -> K (row-major QKb + 1024), 16..23 -> V (V^T [E,M], packed stores).
// 128x128 tiles.
// ---------------------------------------------------------------------------
__global__ __launch_bounds__(256) void gemm_qkv(const __bf16* __restrict__ qbf,
                                                const __bf16* __restrict__ kbf,
                                                const __bf16* __restrict__ vbf,
                                                const __bf16* __restrict__ Wqt,
                                                const __bf16* __restrict__ Wkt,
                                                const __bf16* __restrict__ Wvt,
                                                __bf16* __restrict__ QKb,
                                                __bf16* __restrict__ Vtg,
                                                int M, int K) {
    __shared__ __bf16 As[128 * 64];
    __shared__ __bf16 Bs[128 * 64];
    int tid  = threadIdx.x;
    int lane = tid & 63, wid = tid >> 6;
    int quad = lane >> 4, l15 = lane & 15;
    int waveM = wid >> 1, waveN = wid & 1;
    size_t rowBase = (size_t)blockIdx.y * 128;
    int seg = blockIdx.x >> 3;
    size_t colLoc = (size_t)(blockIdx.x & 7) * 128;

    const __bf16* Ap = seg == 0 ? qbf : seg == 1 ? kbf : vbf;
    const __bf16* Bp = seg == 0 ? Wqt : seg == 1 ? Wkt : Wvt;

    int lrow8  = lane >> 3;
    int lchunk = (lane & 7) ^ lrow8;
    const __bf16* Ag0 = Ap + (rowBase + wid * 32 + lrow8) * (size_t)K + lchunk * 8;
    const __bf16* Bg0 = Bp + (colLoc  + wid * 32 + lrow8) * (size_t)K + lchunk * 8;
    __bf16* AsB = &As[(wid * 32) * 64];
    __bf16* BsB = &Bs[(wid * 32) * 64];

    f32x4 acc[4][4] = {};
    int swz = l15 & 7;

    for (int kb = 0; kb < K; kb += 64) {
        __syncthreads();
        #pragma unroll
        for (int i = 0; i < 4; i++) {
            gll16(Ag0 + (size_t)i * 8 * K + kb, AsB + i * 512);
            gll16(Bg0 + (size_t)i * 8 * K + kb, BsB + i * 512);
        }
        __syncthreads();
        #pragma unroll
        for (int ks = 0; ks < 2; ks++) {
            int p = ((ks * 4 + quad) ^ swz) * 8;
            bf16x8 af[4], bfr[4];
            #pragma unroll
            for (int mi = 0; mi < 4; mi++)
                af[mi] = *(const bf16x8*)&As[(waveM * 64 + mi * 16 + l15) * 64 + p];
            #pragma unroll
            for (int ni = 0; ni < 4; ni++)
                bfr[ni] = *(const bf16x8*)&Bs[(waveN * 64 + ni * 16 + l15) * 64 + p];
            if (seg != 2) {
                #pragma unroll
                for (int mi = 0; mi < 4; mi++)
                    #pragma unroll
                    for (int ni = 0; ni < 4; ni++)
                        acc[mi][ni] = __builtin_amdgcn_mfma_f32_16x16x32_bf16(
                            bfr[ni], af[mi], acc[mi][ni], 0, 0, 0);  // C^T
            } else {
                #pragma unroll
                for (int mi = 0; mi < 4; mi++)
                    #pragma unroll
                    for (int ni = 0; ni < 4; ni++)
                        acc[mi][ni] = __builtin_amdgcn_mfma_f32_16x16x32_bf16(
                            af[mi], bfr[ni], acc[mi][ni], 0, 0, 0);  // C
            }
        }
    }

    if (seg != 2) {
        float sc = seg == 0 ? 0.125f : 1.0f;
        #pragma unroll
        for (int mi = 0; mi < 4; mi++)
        #pragma unroll
        for (int ni = 0; ni < 4; ni++) {
            size_t row = rowBase + waveM * 64 + mi * 16 + l15;
            size_t col = (size_t)seg * 1024 + colLoc + waveN * 64 + ni * 16 + quad * 4;
            bf16x4 pk;
            #pragma unroll
            for (int r = 0; r < 4; r++) pk[r] = (__bf16)(acc[mi][ni][r] * sc);
            *(bf16x4*)&QKb[row * 2048 + col] = pk;
        }
    } else {
        #pragma unroll
        for (int mi = 0; mi < 4; mi++)
        #pragma unroll
        for (int ni = 0; ni < 4; ni++) {
            size_t col = colLoc + waveN * 64 + ni * 16 + l15;        // dim in E
            size_t m0  = rowBase + waveM * 64 + mi * 16 + quad * 4;  // token
            bf16x4 pk;
            #pragma unroll
            for (int r = 0; r < 4; r++) pk[r] = (__bf16)acc[mi][ni][r];
            *(bf16x4*)&Vtg[col * M + m0] = pk;
        }
    }
}

// ---------------------------------------------------------------------------
// Flash attention, transposed-score formulation, 512 threads (8 waves x 16 q).
// Block = 128 Q rows x (b,h). P^T stays in registers; PV B-operand built via
// cross-quad shuffles. K/V via global_load_lds into XOR-swizzled dbuf LDS.
// Q pre-scaled by 1/8. Output O^T -> bf16x4.
// ---------------------------------------------------------------------------
__global__ __launch_bounds__(512, 6) void attn_kernel(const __bf16* __restrict__ QK,
                                                      const __bf16* __restrict__ Vt,
                                                      const int* __restrict__ mask,
                                                      __bf16* __restrict__ Out) {
    const int S = 2048, E = 1024, E2 = 2048, M = 8192;
    int qt = blockIdx.x, bh = blockIdx.y;
    int b = bh >> 4, h = bh & 15;
    int q0 = qt * 128;
    int tid = threadIdx.x, lane = tid & 63, wid = tid >> 6;  // wid 0..7
    int quad = lane >> 4, l15 = lane & 15;

    __shared__ __bf16 KV[2][2 * 4096];  // [buf][Ks 64x64 | Vs 64x64]

    // Q fragments (pre-scaled), used as MFMA B-operands
    bf16x8 aq[2];
    #pragma unroll
    for (int hh = 0; hh < 2; hh++) {
        size_t row = (size_t)(b * S + q0 + wid * 16 + l15);
        aq[hh] = *(const bf16x8*)(QK + row * E2 + h * 64 + hh * 32 + quad * 8);
    }

    int lrow8  = lane >> 3;
    int lchunk = (lane & 7) ^ lrow8;
    // each wave stages 8 K-rows and 8 V-rows per tile
    const __bf16* Kg0 = QK + (size_t)(b * S + wid * 8 + lrow8) * E2 + 1024 + h * 64 + lchunk * 8;
    const __bf16* Vg0 = Vt + (size_t)(h * 64 + wid * 8 + lrow8) * M + b * S + lchunk * 8;

    int srcA = ((quad & 1) * 2) * 16 + l15;
    int srcB = srcA + 16;
    bool selHi = (quad >= 2);
    int swz = l15 & 7;

    f32x4 accO[4] = {};
    float accl = 0.f;

    // prologue: stage tile 0 into buf 0
    gll16(Kg0, &KV[0][wid * 512]);
    gll16(Vg0, &KV[0][4096 + wid * 512]);
    __syncthreads();

    for (int kt = 0; kt < S / 64; kt++) {
        int k0 = kt * 64;
        int buf = kt & 1;
        if (kt + 1 < S / 64) {
            int kn = k0 + 64;
            gll16(Kg0 + (size_t)kn * E2, &KV[buf ^ 1][wid * 512]);
            gll16(Vg0 + kn,              &KV[buf ^ 1][4096 + wid * 512]);
        }
        const __bf16* Ksb = &KV[buf][0];
        const __bf16* Vsb = &KV[buf][4096];

        // S^T tiles: lane holds P^T[key=nt*16+quad*4+r][q=wid*16+l15]
        f32x4 sa[4];
        #pragma unroll
        for (int nt = 0; nt < 4; nt++) {
            bf16x8 a0 = *(const bf16x8*)&Ksb[(nt * 16 + l15) * 64 + ((quad) ^ swz) * 8];
            bf16x8 a1 = *(const bf16x8*)&Ksb[(nt * 16 + l15) * 64 + ((4 + quad) ^ swz) * 8];
            f32x4 a = {};
            a = __builtin_amdgcn_mfma_f32_16x16x32_bf16(a0, aq[0], a, 0, 0, 0);
            a = __builtin_amdgcn_mfma_f32_16x16x32_bf16(a1, aq[1], a, 0, 0, 0);
            sa[nt] = a;
        }

        // mask + exp + pack
        unsigned pd[4][2];
        #pragma unroll
        for (int nt = 0; nt < 4; nt++) {
            int4 mz = *(const int4*)&mask[b * S + k0 + nt * 16 + quad * 4];
            float p0 = mz.x ? __expf(sa[nt][0]) : 0.f;
            float p1 = mz.y ? __expf(sa[nt][1]) : 0.f;
            float p2 = mz.z ? __expf(sa[nt][2]) : 0.f;
            float p3 = mz.w ? __expf(sa[nt][3]) : 0.f;
            accl += (p0 + p1) + (p2 + p3);
            pd[nt][0] = pkbf(p0, p1);
            pd[nt][1] = pkbf(p2, p3);
        }

        // PV B-operand via cross-quad shuffles
        bf16x8 bfrag[2];
        #pragma unroll
        for (int hh = 0; hh < 2; hh++) {
            int ntLo = 2 * hh;
            unsigned dA0 = __shfl((int)pd[ntLo][0], srcA, 64);
            unsigned dB0 = __shfl((int)pd[ntLo + 1][0], srcA, 64);
            unsigned dA1 = __shfl((int)pd[ntLo][1], srcA, 64);
            unsigned dB1 = __shfl((int)pd[ntLo + 1][1], srcA, 64);
            unsigned dA2 = __shfl((int)pd[ntLo][0], srcB, 64);
            unsigned dB2 = __shfl((int)pd[ntLo + 1][0], srcB, 64);
            unsigned dA3 = __shfl((int)pd[ntLo][1], srcB, 64);
            unsigned dB3 = __shfl((int)pd[ntLo + 1][1], srcB, 64);
            union { unsigned u[4]; bf16x8 v; } w;
            w.u[0] = selHi ? dB0 : dA0;
            w.u[1] = selHi ? dB1 : dA1;
            w.u[2] = selHi ? dB2 : dA2;
            w.u[3] = selHi ? dB3 : dA3;
            bfrag[hh] = w.v;
        }

        // O^T += V^T-frag x P^T-frag
        #pragma unroll
        for (int dt = 0; dt < 4; dt++) {
            bf16x8 v0 = *(const bf16x8*)&Vsb[(dt * 16 + l15) * 64 + ((quad) ^ swz) * 8];
            bf16x8 v1 = *(const bf16x8*)&Vsb[(dt * 16 + l15) * 64 + ((4 + quad) ^ swz) * 8];
            accO[dt] = __builtin_amdgcn_mfma_f32_16x16x32_bf16(v0, bfrag[0], accO[dt], 0, 0, 0);
            accO[dt] = __builtin_amdgcn_mfma_f32_16x16x32_bf16(v1, bfrag[1], accO[dt], 0, 0, 0);
        }
        __syncthreads();
    }

    // softmax denominators: keys partitioned across quads
    float l = accl;
    l += __shfl_xor(l, 16, 64);
    l += __shfl_xor(l, 32, 64);
    float inv = 1.0f / l;

    #pragma unroll
    for (int dt = 0; dt < 4; dt++) {
        size_t row = (size_t)(b * S + q0 + wid * 16 + l15);
        bf16x4 pk;
        #pragma unroll
        for (int r = 0; r < 4; r++) pk[r] = (__bf16)(accO[dt][r] * inv);
        *(bf16x4*)&Out[row * E + h * 64 + dt * 16 + quad * 4] = pk;
    }
}

// ---------------------------------------------------------------------------
// Launch
// ---------------------------------------------------------------------------
extern "C" void kernel_launch(void* const* d_in, const int* in_sizes, int n_in,
                              void* d_out, int out_size, void* d_ws, size_t ws_size,
                              hipStream_t stream) {
    const int Bb = 4, S = 2048, E = 1024, FF = 4096;
    const int M = Bb * S;  // 8192

    const float* value = (const float*)d_in[0];
    const float* key   = (const float*)d_in[1];
    const float* query = (const float*)d_in[2];
    const int*   mask  = (const int*)d_in[3];
    const float* Wv    = (const float*)d_in[4];
    const float* Wk    = (const float*)d_in[5];
    const float* Wq    = (const float*)d_in[6];
    const float* Wo    = (const float*)d_in[7];
    const float* bo    = (const float*)d_in[8];
    const float* ln1_g = (const float*)d_in[9];
    const float* ln1_b = (const float*)d_in[10];
    const float* ln2_g = (const float*)d_in[11];
    const float* ln2_b = (const float*)d_in[12];
    const float* lnf_g = (const float*)d_in[13];
    const float* lnf_b = (const float*)d_in[14];
    const float* W1    = (const float*)d_in[15];
    const float* b1    = (const float*)d_in[16];
    const float* W2    = (const float*)d_in[17];
    const float* b2    = (const float*)d_in[18];

    char* ws = (char*)d_ws;
    const size_t MB = 1024 * 1024;
    __bf16* Wqt = (__bf16*)(ws + 0 * MB);
    __bf16* Wkt = (__bf16*)(ws + 2 * MB);
    __bf16* Wvt = (__bf16*)(ws + 4 * MB);
    __bf16* Wot = (__bf16*)(ws + 6 * MB);
    __bf16* W1t = (__bf16*)(ws + 8 * MB);    // [FF, E]
    __bf16* W2t = (__bf16*)(ws + 16 * MB);   // [E, FF]
    __bf16* q_bf = (__bf16*)(ws + 24 * MB);
    __bf16* k_bf = (__bf16*)(ws + 40 * MB);
    __bf16* v_bf = (__bf16*)(ws + 56 * MB);
    __bf16* QKb  = (__bf16*)(ws + 72 * MB);  // [M, 2E]
    __bf16* Vtg  = (__bf16*)(ws + 104 * MB); // V^T [E, M]
    __bf16* attn = q_bf;
    __bf16* x_ln = k_bf;
    __bf16* h1   = v_bf;                     // [M, FF] 64MB
    float*  qln  = (float*)(ws + 120 * MB);
    float*  x32  = (float*)(ws + 152 * MB);

    transpose_all<<<12288, 256, 0, stream>>>(Wq, Wk, Wv, Wo, W1, W2,
                                             Wqt, Wkt, Wvt, Wot, W1t, W2t);

    ln3_kernel<<<dim3(M, 3), 256, 0, stream>>>(query, key, value,
                                               ln1_g, ln1_b, ln2_g, ln2_b,
                                               qln, q_bf, k_bf, v_bf);

    gemm_qkv<<<dim3(24, M / 128), 256, 0, stream>>>(q_bf, k_bf, v_bf,
                                                    Wqt, Wkt, Wvt, QKb, Vtg, M, E);

    attn_kernel<<<dim3(S / 128, Bb * 16), 512, 0, stream>>>(QKb, Vtg, mask, attn);

    // out proj + bias + residual(qln) -> x32 (f32). 128x64 tiles, grid 1024.
    gemm_tn<1, 4, 2><<<dim3(E / 64, M / 128), 256, 0, stream>>>(
        attn, Wot, bo, qln, x32, M, E, E);

    ln_kernel<<<M, 256, 0, stream>>>(x32, lnf_g, lnf_b, x_ln);

    // FFN1: 128x128 tiles, grid 2048
    gemm_tn<2, 4, 4><<<dim3(FF / 128, M / 128), 256, 0, stream>>>(
        x_ln, W1t, b1, nullptr, h1, M, FF, E);
    // FFN2: 128x64 tiles, grid 1024
    gemm_tn<1, 4, 2><<<dim3(E / 64, M / 128), 256, 0, stream>>>(
        h1, W2t, b2, x32, (float*)d_out, M, E, FF);
}

// Round 5
// 666.378 us; speedup vs baseline: 1.1389x; 1.1389x over previous
//
#include <hip/hip_runtime.h>
#include <hip/hip_bf16.h>
#include <math.h>

typedef __bf16 bf16x8 __attribute__((ext_vector_type(8)));
typedef __bf16 bf16x4 __attribute__((ext_vector_type(4)));
typedef float f32x4 __attribute__((ext_vector_type(4)));

#define AS1 __attribute__((address_space(1)))
#define AS3 __attribute__((address_space(3)))

__device__ __forceinline__ void gll16(const __bf16* g, __bf16* l) {
    __builtin_amdgcn_global_load_lds((const AS1 unsigned int*)g,
                                     (AS3 unsigned int*)l, 16, 0, 0);
}

__device__ __forceinline__ unsigned pkbf(float a, float b) {
    union { __bf16 h[2]; unsigned u; } t;
    t.h[0] = (__bf16)a; t.h[1] = (__bf16)b;
    return t.u;
}

// ---------------------------------------------------------------------------
// All 6 weight transposes (fp32 [K,N] -> bf16 [N,K]) in one launch.
// ---------------------------------------------------------------------------
__global__ __launch_bounds__(256) void transpose_all(
    const float* __restrict__ Wq, const float* __restrict__ Wk,
    const float* __restrict__ Wv, const float* __restrict__ Wo,
    const float* __restrict__ W1, const float* __restrict__ W2,
    __bf16* __restrict__ Wqt, __bf16* __restrict__ Wkt,
    __bf16* __restrict__ Wvt, __bf16* __restrict__ Wot,
    __bf16* __restrict__ W1t, __bf16* __restrict__ W2t) {
    int g = blockIdx.x;
    const float* W; __bf16* Wt; int K, N, kt, nt;
    if (g < 4096) {
        int mi = g >> 10, loc = g & 1023;
        K = 1024; N = 1024; kt = loc >> 5; nt = loc & 31;
        W  = mi == 0 ? Wq  : mi == 1 ? Wk  : mi == 2 ? Wv  : Wo;
        Wt = mi == 0 ? Wqt : mi == 1 ? Wkt : mi == 2 ? Wvt : Wot;
    } else if (g < 8192) {
        int loc = g - 4096; W = W1; Wt = W1t;
        K = 1024; N = 4096; kt = loc >> 7; nt = loc & 127;
    } else {
        int loc = g - 8192; W = W2; Wt = W2t;
        K = 4096; N = 1024; kt = loc >> 5; nt = loc & 31;
    }
    int k0 = kt * 32, n0 = nt * 32;
    __shared__ float tile[32][33];
    int tx = threadIdx.x & 31, ty = threadIdx.x >> 5;
    #pragma unroll
    for (int j = ty; j < 32; j += 8)
        tile[j][tx] = W[(size_t)(k0 + j) * N + n0 + tx];
    __syncthreads();
    #pragma unroll
    for (int j = ty; j < 32; j += 8)
        Wt[(size_t)(n0 + j) * K + k0 + tx] = (__bf16)tile[tx][j];
}

// ---------------------------------------------------------------------------
// Fused 3-way pre-norm.
// ---------------------------------------------------------------------------
__global__ __launch_bounds__(256) void ln3_kernel(
    const float* __restrict__ q, const float* __restrict__ k,
    const float* __restrict__ v,
    const float* __restrict__ g1, const float* __restrict__ b1,
    const float* __restrict__ g2, const float* __restrict__ b2,
    float* __restrict__ qln, __bf16* __restrict__ qbf,
    __bf16* __restrict__ kbf, __bf16* __restrict__ vbf) {
    const int E = 1024;
    int which = blockIdx.y;
    const float* x = which == 0 ? q : which == 1 ? k : v;
    const float* g = which == 0 ? g1 : g2;
    const float* bb = which == 0 ? b1 : b2;
    float* o32 = which == 0 ? qln : nullptr;
    __bf16* obf = which == 0 ? qbf : which == 1 ? kbf : vbf;

    size_t row = blockIdx.x;
    int t = threadIdx.x;
    float4 val = ((const float4*)(x + row * E))[t];
    float s  = val.x + val.y + val.z + val.w;
    float s2 = val.x * val.x + val.y * val.y + val.z * val.z + val.w * val.w;
    #pragma unroll
    for (int off = 32; off >= 1; off >>= 1) {
        s  += __shfl_down(s, off);
        s2 += __shfl_down(s2, off);
    }
    __shared__ float red[2][4];
    int wid = t >> 6, lane = t & 63;
    if (lane == 0) { red[0][wid] = s; red[1][wid] = s2; }
    __syncthreads();
    if (t == 0) {
        float S1 = red[0][0] + red[0][1] + red[0][2] + red[0][3];
        float S2 = red[1][0] + red[1][1] + red[1][2] + red[1][3];
        float mean = S1 / E;
        float var  = S2 / E - mean * mean;
        red[0][0] = mean;
        red[1][0] = 1.0f / sqrtf(var + 1e-5f);
    }
    __syncthreads();
    float mean = red[0][0], rstd = red[1][0];
    float4 gv = ((const float4*)g)[t];
    float4 bv = ((const float4*)bb)[t];
    float y0 = (val.x - mean) * rstd * gv.x + bv.x;
    float y1 = (val.y - mean) * rstd * gv.y + bv.y;
    float y2 = (val.z - mean) * rstd * gv.z + bv.z;
    float y3 = (val.w - mean) * rstd * gv.w + bv.w;
    if (o32) ((float4*)(o32 + row * E))[t] = make_float4(y0, y1, y2, y3);
    bf16x4 o;
    o[0] = (__bf16)y0; o[1] = (__bf16)y1; o[2] = (__bf16)y2; o[3] = (__bf16)y3;
    ((bf16x4*)(obf + row * E))[t] = o;
}

// single-input LN (final norm), bf16 out
__global__ __launch_bounds__(256) void ln_kernel(const float* __restrict__ x,
                                                 const float* __restrict__ g,
                                                 const float* __restrict__ bb,
                                                 __bf16* __restrict__ outbf) {
    const int E = 1024;
    size_t row = blockIdx.x;
    int t = threadIdx.x;
    float4 v = ((const float4*)(x + row * E))[t];
    float s  = v.x + v.y + v.z + v.w;
    float s2 = v.x * v.x + v.y * v.y + v.z * v.z + v.w * v.w;
    #pragma unroll
    for (int off = 32; off >= 1; off >>= 1) {
        s  += __shfl_down(s, off);
        s2 += __shfl_down(s2, off);
    }
    __shared__ float red[2][4];
    int wid = t >> 6, lane = t & 63;
    if (lane == 0) { red[0][wid] = s; red[1][wid] = s2; }
    __syncthreads();
    if (t == 0) {
        float S1 = red[0][0] + red[0][1] + red[0][2] + red[0][3];
        float S2 = red[1][0] + red[1][1] + red[1][2] + red[1][3];
        float mean = S1 / E;
        float var  = S2 / E - mean * mean;
        red[0][0] = mean;
        red[1][0] = 1.0f / sqrtf(var + 1e-5f);
    }
    __syncthreads();
    float mean = red[0][0], rstd = red[1][0];
    float4 gv = ((const float4*)g)[t];
    float4 bv = ((const float4*)bb)[t];
    bf16x4 o;
    o[0] = (__bf16)((v.x - mean) * rstd * gv.x + bv.x);
    o[1] = (__bf16)((v.y - mean) * rstd * gv.y + bv.y);
    o[2] = (__bf16)((v.z - mean) * rstd * gv.z + bv.z);
    o[3] = (__bf16)((v.w - mean) * rstd * gv.w + bv.w);
    ((bf16x4*)(outbf + row * E))[t] = o;
}

// ---------------------------------------------------------------------------
// GEMM 128x128 tile, 1D grid with XCD row-affinity swizzle:
//   x8 = id&7 (assumed XCD), col = (id>>3)%GX, row = ((id>>3)/GX)*8 + x8.
// All blocks of one row-panel land on one XCD -> A-panel fetched once/XCD.
// Swapped-operand MFMA (C^T accum layout: lane row=l15, col=quad*4+r).
// Column split at splitN selects (A2,Bt2) for merged QK.
// EPI: 0 bf16*sc out; 1 f32+bias+resid; 2 bf16+bias+gelu.
// ---------------------------------------------------------------------------
template <int EPI>
__global__ __launch_bounds__(256) void gemm128(const __bf16* __restrict__ A,
                                               const __bf16* __restrict__ A2,
                                               const __bf16* __restrict__ Bt,
                                               const __bf16* __restrict__ Bt2,
                                               const float* __restrict__ bias,
                                               const float* __restrict__ resid,
                                               void* __restrict__ Cout,
                                               int M, int N, int K,
                                               int splitN, float scale) {
    __shared__ __bf16 As[128 * 64];
    __shared__ __bf16 Bs[128 * 64];
    int tid  = threadIdx.x;
    int lane = tid & 63, wid = tid >> 6;
    int quad = lane >> 4, l15 = lane & 15;
    int waveM = wid >> 1, waveN = wid & 1;

    int GX = N >> 7;
    int id = blockIdx.x;
    int x8 = id & 7, t = id >> 3;
    size_t rowBase = (size_t)((t / GX) * 8 + x8) * 128;
    size_t colBase = (size_t)(t % GX) * 128;

    const __bf16* Ap = A; const __bf16* Bp = Bt;
    size_t colLoc = colBase;
    float sc = scale;
    if ((int)colBase >= splitN) { Ap = A2; Bp = Bt2; colLoc = colBase - splitN; sc = 1.0f; }

    int lrow8  = lane >> 3;
    int lchunk = (lane & 7) ^ lrow8;
    const __bf16* Ag0 = Ap + (rowBase + wid * 32 + lrow8) * (size_t)K + lchunk * 8;
    const __bf16* Bg0 = Bp + (colLoc  + wid * 32 + lrow8) * (size_t)K + lchunk * 8;
    __bf16* AsB = &As[(wid * 32) * 64];
    __bf16* BsB = &Bs[(wid * 32) * 64];

    f32x4 acc[4][4] = {};
    int swz = l15 & 7;

    for (int kb = 0; kb < K; kb += 64) {
        __syncthreads();
        #pragma unroll
        for (int i = 0; i < 4; i++) {
            gll16(Ag0 + (size_t)i * 8 * K + kb, AsB + i * 512);
            gll16(Bg0 + (size_t)i * 8 * K + kb, BsB + i * 512);
        }
        __syncthreads();
        #pragma unroll
        for (int ks = 0; ks < 2; ks++) {
            int p = ((ks * 4 + quad) ^ swz) * 8;
            bf16x8 af[4], bfr[4];
            #pragma unroll
            for (int mi = 0; mi < 4; mi++)
                af[mi] = *(const bf16x8*)&As[(waveM * 64 + mi * 16 + l15) * 64 + p];
            #pragma unroll
            for (int ni = 0; ni < 4; ni++)
                bfr[ni] = *(const bf16x8*)&Bs[(waveN * 64 + ni * 16 + l15) * 64 + p];
            #pragma unroll
            for (int mi = 0; mi < 4; mi++)
                #pragma unroll
                for (int ni = 0; ni < 4; ni++)
                    acc[mi][ni] = __builtin_amdgcn_mfma_f32_16x16x32_bf16(
                        bfr[ni], af[mi], acc[mi][ni], 0, 0, 0);  // swapped: C^T
        }
    }

    #pragma unroll
    for (int mi = 0; mi < 4; mi++)
    #pragma unroll
    for (int ni = 0; ni < 4; ni++) {
        size_t row = rowBase + waveM * 64 + mi * 16 + l15;
        size_t col = colBase + waveN * 64 + ni * 16 + quad * 4;
        f32x4 v = acc[mi][ni];
        if (EPI == 1) {
            float4 b4 = *(const float4*)&bias[col];
            float4 r4 = *(const float4*)&resid[row * N + col];
            float4 o;
            o.x = v[0] + b4.x + r4.x; o.y = v[1] + b4.y + r4.y;
            o.z = v[2] + b4.z + r4.z; o.w = v[3] + b4.w + r4.w;
            *(float4*)&((float*)Cout)[row * N + col] = o;
        } else if (EPI == 2) {
            float4 b4 = *(const float4*)&bias[col];
            bf16x4 pk;
            #pragma unroll
            for (int r = 0; r < 4; r++) {
                float t2 = v[r] + ((const float*)&b4)[r];
                pk[r] = (__bf16)(0.5f * t2 * (1.0f + erff(t2 * 0.70710678118654752f)));
            }
            *(bf16x4*)&((__bf16*)Cout)[row * N + col] = pk;
        } else {
            bf16x4 pk;
            #pragma unroll
            for (int r = 0; r < 4; r++) pk[r] = (__bf16)(v[r] * sc);
            *(bf16x4*)&((__bf16*)Cout)[row * N + col] = pk;
        }
    }
}

// ---------------------------------------------------------------------------
// V projection GEMM (non-swapped MFMA) writing V^T [E, M], packed stores.
// Same XCD row-affinity swizzle.
// ---------------------------------------------------------------------------
__global__ __launch_bounds__(256) void gemmV(const __bf16* __restrict__ A,
                                             const __bf16* __restrict__ Bt,
                                             __bf16* __restrict__ Cout,
                                             int M, int N, int K) {
    __shared__ __bf16 As[128 * 64];
    __shared__ __bf16 Bs[128 * 64];
    int tid  = threadIdx.x;
    int lane = tid & 63, wid = tid >> 6;
    int quad = lane >> 4, l15 = lane & 15;
    int waveM = wid >> 1, waveN = wid & 1;

    int GX = N >> 7;
    int id = blockIdx.x;
    int x8 = id & 7, t = id >> 3;
    size_t rowBase = (size_t)((t / GX) * 8 + x8) * 128;
    size_t colBase = (size_t)(t % GX) * 128;

    int lrow8  = lane >> 3;
    int lchunk = (lane & 7) ^ lrow8;
    const __bf16* Ag0 = A  + (rowBase + wid * 32 + lrow8) * (size_t)K + lchunk * 8;
    const __bf16* Bg0 = Bt + (colBase + wid * 32 + lrow8) * (size_t)K + lchunk * 8;
    __bf16* AsB = &As[(wid * 32) * 64];
    __bf16* BsB = &Bs[(wid * 32) * 64];

    f32x4 acc[4][4] = {};
    int swz = l15 & 7;

    for (int kb = 0; kb < K; kb += 64) {
        __syncthreads();
        #pragma unroll
        for (int i = 0; i < 4; i++) {
            gll16(Ag0 + (size_t)i * 8 * K + kb, AsB + i * 512);
            gll16(Bg0 + (size_t)i * 8 * K + kb, BsB + i * 512);
        }
        __syncthreads();
        #pragma unroll
        for (int ks = 0; ks < 2; ks++) {
            int p = ((ks * 4 + quad) ^ swz) * 8;
            bf16x8 af[4], bfr[4];
            #pragma unroll
            for (int mi = 0; mi < 4; mi++)
                af[mi] = *(const bf16x8*)&As[(waveM * 64 + mi * 16 + l15) * 64 + p];
            #pragma unroll
            for (int ni = 0; ni < 4; ni++)
                bfr[ni] = *(const bf16x8*)&Bs[(waveN * 64 + ni * 16 + l15) * 64 + p];
            #pragma unroll
            for (int mi = 0; mi < 4; mi++)
                #pragma unroll
                for (int ni = 0; ni < 4; ni++)
                    acc[mi][ni] = __builtin_amdgcn_mfma_f32_16x16x32_bf16(
                        af[mi], bfr[ni], acc[mi][ni], 0, 0, 0);
        }
    }

    #pragma unroll
    for (int mi = 0; mi < 4; mi++)
    #pragma unroll
    for (int ni = 0; ni < 4; ni++) {
        size_t col = colBase + waveN * 64 + ni * 16 + l15;        // dim in E
        size_t m0  = rowBase + waveM * 64 + mi * 16 + quad * 4;   // token
        bf16x4 pk;
        #pragma unroll
        for (int r = 0; r < 4; r++) pk[r] = (__bf16)acc[mi][ni][r];
        *(bf16x4*)&Cout[col * M + m0] = pk;
    }
}

// ---------------------------------------------------------------------------
// Flash attention, transposed-score formulation, 512 threads (8 waves x 16 q).
// ---------------------------------------------------------------------------
__global__ __launch_bounds__(512, 6) void attn_kernel(const __bf16* __restrict__ QK,
                                                      const __bf16* __restrict__ Vt,
                                                      const int* __restrict__ mask,
                                                      __bf16* __restrict__ Out) {
    const int S = 2048, E = 1024, E2 = 2048, M = 8192;
    int qt = blockIdx.x, bh = blockIdx.y;
    int b = bh >> 4, h = bh & 15;
    int q0 = qt * 128;
    int tid = threadIdx.x, lane = tid & 63, wid = tid >> 6;  // wid 0..7
    int quad = lane >> 4, l15 = lane & 15;

    __shared__ __bf16 KV[2][2 * 4096];  // [buf][Ks 64x64 | Vs 64x64]

    bf16x8 aq[2];
    #pragma unroll
    for (int hh = 0; hh < 2; hh++) {
        size_t row = (size_t)(b * S + q0 + wid * 16 + l15);
        aq[hh] = *(const bf16x8*)(QK + row * E2 + h * 64 + hh * 32 + quad * 8);
    }

    int lrow8  = lane >> 3;
    int lchunk = (lane & 7) ^ lrow8;
    const __bf16* Kg0 = QK + (size_t)(b * S + wid * 8 + lrow8) * E2 + 1024 + h * 64 + lchunk * 8;
    const __bf16* Vg0 = Vt + (size_t)(h * 64 + wid * 8 + lrow8) * M + b * S + lchunk * 8;

    int srcA = ((quad & 1) * 2) * 16 + l15;
    int srcB = srcA + 16;
    bool selHi = (quad >= 2);
    int swz = l15 & 7;

    f32x4 accO[4] = {};
    float accl = 0.f;

    gll16(Kg0, &KV[0][wid * 512]);
    gll16(Vg0, &KV[0][4096 + wid * 512]);
    __syncthreads();

    for (int kt = 0; kt < S / 64; kt++) {
        int k0 = kt * 64;
        int buf = kt & 1;
        if (kt + 1 < S / 64) {
            int kn = k0 + 64;
            gll16(Kg0 + (size_t)kn * E2, &KV[buf ^ 1][wid * 512]);
            gll16(Vg0 + kn,              &KV[buf ^ 1][4096 + wid * 512]);
        }
        const __bf16* Ksb = &KV[buf][0];
        const __bf16* Vsb = &KV[buf][4096];

        f32x4 sa[4];
        #pragma unroll
        for (int nt = 0; nt < 4; nt++) {
            bf16x8 a0 = *(const bf16x8*)&Ksb[(nt * 16 + l15) * 64 + ((quad) ^ swz) * 8];
            bf16x8 a1 = *(const bf16x8*)&Ksb[(nt * 16 + l15) * 64 + ((4 + quad) ^ swz) * 8];
            f32x4 a = {};
            a = __builtin_amdgcn_mfma_f32_16x16x32_bf16(a0, aq[0], a, 0, 0, 0);
            a = __builtin_amdgcn_mfma_f32_16x16x32_bf16(a1, aq[1], a, 0, 0, 0);
            sa[nt] = a;
        }

        unsigned pd[4][2];
        #pragma unroll
        for (int nt = 0; nt < 4; nt++) {
            int4 mz = *(const int4*)&mask[b * S + k0 + nt * 16 + quad * 4];
            float p0 = mz.x ? __expf(sa[nt][0]) : 0.f;
            float p1 = mz.y ? __expf(sa[nt][1]) : 0.f;
            float p2 = mz.z ? __expf(sa[nt][2]) : 0.f;
            float p3 = mz.w ? __expf(sa[nt][3]) : 0.f;
            accl += (p0 + p1) + (p2 + p3);
            pd[nt][0] = pkbf(p0, p1);
            pd[nt][1] = pkbf(p2, p3);
        }

        bf16x8 bfrag[2];
        #pragma unroll
        for (int hh = 0; hh < 2; hh++) {
            int ntLo = 2 * hh;
            unsigned dA0 = __shfl((int)pd[ntLo][0], srcA, 64);
            unsigned dB0 = __shfl((int)pd[ntLo + 1][0], srcA, 64);
            unsigned dA1 = __shfl((int)pd[ntLo][1], srcA, 64);
            unsigned dB1 = __shfl((int)pd[ntLo + 1][1], srcA, 64);
            unsigned dA2 = __shfl((int)pd[ntLo][0], srcB, 64);
            unsigned dB2 = __shfl((int)pd[ntLo + 1][0], srcB, 64);
            unsigned dA3 = __shfl((int)pd[ntLo][1], srcB, 64);
            unsigned dB3 = __shfl((int)pd[ntLo + 1][1], srcB, 64);
            union { unsigned u[4]; bf16x8 v; } w;
            w.u[0] = selHi ? dB0 : dA0;
            w.u[1] = selHi ? dB1 : dA1;
            w.u[2] = selHi ? dB2 : dA2;
            w.u[3] = selHi ? dB3 : dA3;
            bfrag[hh] = w.v;
        }

        #pragma unroll
        for (int dt = 0; dt < 4; dt++) {
            bf16x8 v0 = *(const bf16x8*)&Vsb[(dt * 16 + l15) * 64 + ((quad) ^ swz) * 8];
            bf16x8 v1 = *(const bf16x8*)&Vsb[(dt * 16 + l15) * 64 + ((4 + quad) ^ swz) * 8];
            accO[dt] = __builtin_amdgcn_mfma_f32_16x16x32_bf16(v0, bfrag[0], accO[dt], 0, 0, 0);
            accO[dt] = __builtin_amdgcn_mfma_f32_16x16x32_bf16(v1, bfrag[1], accO[dt], 0, 0, 0);
        }
        __syncthreads();
    }

    float l = accl;
    l += __shfl_xor(l, 16, 64);
    l += __shfl_xor(l, 32, 64);
    float inv = 1.0f / l;

    #pragma unroll
    for (int dt = 0; dt < 4; dt++) {
        size_t row = (size_t)(b * S + q0 + wid * 16 + l15);
        bf16x4 pk;
        #pragma unroll
        for (int r = 0; r < 4; r++) pk[r] = (__bf16)(accO[dt][r] * inv);
        *(bf16x4*)&Out[row * E + h * 64 + dt * 16 + quad * 4] = pk;
    }
}

// ---------------------------------------------------------------------------
// Launch
// ---------------------------------------------------------------------------
extern "C" void kernel_launch(void* const* d_in, const int* in_sizes, int n_in,
                              void* d_out, int out_size, void* d_ws, size_t ws_size,
                              hipStream_t stream) {
    const int Bb = 4, S = 2048, E = 1024, FF = 4096;
    const int M = Bb * S;  // 8192

    const float* value = (const float*)d_in[0];
    const float* key   = (const float*)d_in[1];
    const float* query = (const float*)d_in[2];
    const int*   mask  = (const int*)d_in[3];
    const float* Wv    = (const float*)d_in[4];
    const float* Wk    = (const float*)d_in[5];
    const float* Wq    = (const float*)d_in[6];
    const float* Wo    = (const float*)d_in[7];
    const float* bo    = (const float*)d_in[8];
    const float* ln1_g = (const float*)d_in[9];
    const float* ln1_b = (const float*)d_in[10];
    const float* ln2_g = (const float*)d_in[11];
    const float* ln2_b = (const float*)d_in[12];
    const float* lnf_g = (const float*)d_in[13];
    const float* lnf_b = (const float*)d_in[14];
    const float* W1    = (const float*)d_in[15];
    const float* b1    = (const float*)d_in[16];
    const float* W2    = (const float*)d_in[17];
    const float* b2    = (const float*)d_in[18];

    char* ws = (char*)d_ws;
    const size_t MB = 1024 * 1024;
    __bf16* Wqt = (__bf16*)(ws + 0 * MB);
    __bf16* Wkt = (__bf16*)(ws + 2 * MB);
    __bf16* Wvt = (__bf16*)(ws + 4 * MB);
    __bf16* Wot = (__bf16*)(ws + 6 * MB);
    __bf16* W1t = (__bf16*)(ws + 8 * MB);    // [FF, E]
    __bf16* W2t = (__bf16*)(ws + 16 * MB);   // [E, FF]
    __bf16* q_bf = (__bf16*)(ws + 24 * MB);
    __bf16* k_bf = (__bf16*)(ws + 40 * MB);
    __bf16* v_bf = (__bf16*)(ws + 56 * MB);
    __bf16* QKb  = (__bf16*)(ws + 72 * MB);  // [M, 2E]
    __bf16* Vtg  = (__bf16*)(ws + 104 * MB); // V^T [E, M]
    __bf16* attn = q_bf;
    __bf16* x_ln = k_bf;
    __bf16* h1   = v_bf;                     // [M, FF] 64MB
    float*  qln  = (float*)(ws + 120 * MB);
    float*  x32  = (float*)(ws + 152 * MB);

    transpose_all<<<12288, 256, 0, stream>>>(Wq, Wk, Wv, Wo, W1, W2,
                                             Wqt, Wkt, Wvt, Wot, W1t, W2t);

    ln3_kernel<<<dim3(M, 3), 256, 0, stream>>>(query, key, value,
                                               ln1_g, ln1_b, ln2_g, ln2_b,
                                               qln, q_bf, k_bf, v_bf);

    // merged Q|K projection -> QKb [M, 2E]; Q side scaled 1/8. grid 16*64.
    gemm128<0><<<16 * 64, 256, 0, stream>>>(
        q_bf, k_bf, Wqt, Wkt, nullptr, nullptr, QKb, M, 2 * E, E, E, 0.125f);

    // V projection -> V^T [E, M]. grid 8*64.
    gemmV<<<8 * 64, 256, 0, stream>>>(v_bf, Wvt, Vtg, M, E, E);

    attn_kernel<<<dim3(S / 128, Bb * 16), 512, 0, stream>>>(QKb, Vtg, mask, attn);

    // out proj + bias + residual(qln) -> x32 (f32). grid 8*64.
    gemm128<1><<<8 * 64, 256, 0, stream>>>(
        attn, attn, Wot, Wot, bo, qln, x32, M, E, E, E, 1.0f);

    ln_kernel<<<M, 256, 0, stream>>>(x32, lnf_g, lnf_b, x_ln);

    // FFN1: grid 32*64.
    gemm128<2><<<32 * 64, 256, 0, stream>>>(
        x_ln, x_ln, W1t, W1t, b1, nullptr, h1, M, FF, E, FF, 1.0f);
    // FFN2: grid 8*64.
    gemm128<1><<<8 * 64, 256, 0, stream>>>(
        h1, h1, W2t, W2t, b2, x32, (float*)d_out, M, E, FF, E, 1.0f);
}